// Round 1
// baseline (10401.355 us; speedup 1.0000x reference)
//
#include <hip/hip_runtime.h>

// ---------------- constants ----------------
static const size_t OFF_ATT = 20480;    // output section sizes: out 1024*10*2
static const size_t OFF_H   = 122880;   // + att 1024*10*10
static const size_t OFF_C   = 385024;   // + h 2*1024*128

__device__ __forceinline__ float sigf(float x) { return 1.0f / (1.0f + __expf(-x)); }
// tanh(x) = 1 - 2/(e^{2x}+1); safe at +/-inf (no NaN), ~1e-7 abs err near 0.
__device__ __forceinline__ float tanhfast(float x) { return 1.0f - 2.0f / (__expf(2.0f * x) + 1.0f); }

// ---------------- prep kernels ----------------
// W[R][C] -> Tm[C][R]
__global__ __launch_bounds__(256) void transpose_k(const float* __restrict__ W, float* __restrict__ Tm, int R, int C) {
    int idx = blockIdx.x * 256 + threadIdx.x;
    if (idx < R * C) {
        int r = idx / C, c = idx - r * C;
        Tm[(size_t)c * R + r] = W[idx];
    }
}

__global__ void bias_comb_k(const float* __restrict__ bih, const float* __restrict__ bhh,
                            float* __restrict__ b0, float* __restrict__ b1) {
    int i = blockIdx.x * 256 + threadIdx.x;
    if (i < 512) {
        b0[i] = bih[i] + bhh[i];
        b1[i] = bih[512 + i] + bhh[512 + i];
    }
}

// ---------------- tiled GEMM: C = act(A[M,K] @ B[N,K]^T + bias[N]) ----------------
__global__ __launch_bounds__(256) void gemm_bias_act_k(const float* __restrict__ A, const float* __restrict__ Bm,
                                                       const float* __restrict__ bias, float* __restrict__ C,
                                                       int M, int N, int K, int relu) {
    __shared__ float As[16][68];
    __shared__ float Bs[16][68];
    int tid = threadIdx.x;
    int tx = tid & 15, ty = tid >> 4;
    int bm = blockIdx.y << 6, bn = blockIdx.x << 6;
    int lr = tid >> 2, lk = (tid & 3) << 2;
    float acc[4][4] = {};
    for (int k0 = 0; k0 < K; k0 += 16) {
        __syncthreads();
        float4 av = *(const float4*)(A + (size_t)(bm + lr) * K + k0 + lk);
        float4 bv = *(const float4*)(Bm + (size_t)(bn + lr) * K + k0 + lk);
        As[lk + 0][lr] = av.x; As[lk + 1][lr] = av.y; As[lk + 2][lr] = av.z; As[lk + 3][lr] = av.w;
        Bs[lk + 0][lr] = bv.x; Bs[lk + 1][lr] = bv.y; Bs[lk + 2][lr] = bv.z; Bs[lk + 3][lr] = bv.w;
        __syncthreads();
#pragma unroll
        for (int kk = 0; kk < 16; ++kk) {
            float a[4], b[4];
#pragma unroll
            for (int i = 0; i < 4; ++i) a[i] = As[kk][ty * 4 + i];
#pragma unroll
            for (int j = 0; j < 4; ++j) b[j] = Bs[kk][tx * 4 + j];
#pragma unroll
            for (int i = 0; i < 4; ++i)
#pragma unroll
                for (int j = 0; j < 4; ++j) acc[i][j] = fmaf(a[i], b[j], acc[i][j]);
        }
    }
#pragma unroll
    for (int i = 0; i < 4; ++i)
#pragma unroll
        for (int j = 0; j < 4; ++j) {
            float v = acc[i][j] + bias[bn + tx * 4 + j];
            if (relu) v = fmaxf(v, 0.0f);
            C[(size_t)(bm + ty * 4 + i) * N + bn + tx * 4 + j] = v;
        }
}

// ---------------- main sequential kernel ----------------
// 256 blocks x 256 threads; block owns 4 batch rows. Entire recurrence + attention is
// row-local, so only __syncthreads() needed between steps.
__global__ __launch_bounds__(256) void recurrent_k(
    const float* __restrict__ xg0,    // [1024*10][512] = lstm_in@Wih0^T + bih0 + bhh0
    const float* __restrict__ WhhT0,  // [128][512]
    const float* __restrict__ WihT1,  // [128][512]
    const float* __restrict__ WhhT1,  // [128][512]
    const float* __restrict__ bias1,  // [512] = bih1+bhh1
    const float* __restrict__ WqT, const float* __restrict__ bq,    // [128][128],[128]
    const float* __restrict__ WkT, const float* __restrict__ bk,    // [128][128],[128]
    const float* __restrict__ Wo1T, const float* __restrict__ bo1,  // [128][64],[64]
    const float* __restrict__ Wo2, const float* __restrict__ bo2,   // [2][64],[2]
    const float* __restrict__ gv, const float* __restrict__ uv,     // flat [2][1024][128]
    float* __restrict__ out) {
    __shared__ float h0s[4][128], c0s[4][128], h1s[4][128], c1s[4][128];
    __shared__ float Ms[4][10][128];
    __shared__ float qs[4][128];
    __shared__ float Kms[4][10][128];
    __shared__ float us[4][64];
    __shared__ float scs[4][10];

    const int tid = threadIdx.x;
    const int row = tid >> 6;   // wave == row
    const int jp  = tid & 63;
    const int j0  = jp * 2;
    const int b   = blockIdx.x * 4 + row;

    {   // init states from the flat [L,B,H] reinterpretation
        const size_t base = (size_t)b * 128 + j0;
        *(float2*)&h0s[row][j0] = *(const float2*)(gv + base);
        *(float2*)&h1s[row][j0] = *(const float2*)(gv + 131072 + base);
        *(float2*)&c0s[row][j0] = *(const float2*)(uv + base);
        *(float2*)&c1s[row][j0] = *(const float2*)(uv + 131072 + base);
    }
    __syncthreads();

    for (int r = 0; r < 10; ++r) {
        for (int hist = 0; hist <= r; ++hist) {
            const int t0 = (hist <= 1) ? 0 : hist;   // quirk: hist==1 reruns full prefix
            for (int t = t0; t <= r; ++t) {
                // ---------- layer 0: gates = xg0[b,t] + h0 @ Whh0^T ----------
                float a00, a01, a02, a03, a10, a11, a12, a13;
                {
                    const float* xg = xg0 + ((size_t)b * 10 + t) * 512 + j0;
                    float2 v0 = *(const float2*)(xg);
                    float2 v1 = *(const float2*)(xg + 128);
                    float2 v2 = *(const float2*)(xg + 256);
                    float2 v3 = *(const float2*)(xg + 384);
                    a00 = v0.x; a10 = v0.y; a01 = v1.x; a11 = v1.y;
                    a02 = v2.x; a12 = v2.y; a03 = v3.x; a13 = v3.y;
                }
                for (int k = 0; k < 128; k += 4) {
                    float4 hv = *(const float4*)&h0s[row][k];
                    float ha[4] = {hv.x, hv.y, hv.z, hv.w};
                    const float* wb = WhhT0 + (size_t)k * 512 + j0;
#pragma unroll
                    for (int kk = 0; kk < 4; ++kk) {
                        float hk = ha[kk];
                        const float* w = wb + kk * 512;
                        float2 w0 = *(const float2*)(w);
                        float2 w1 = *(const float2*)(w + 128);
                        float2 w2 = *(const float2*)(w + 256);
                        float2 w3 = *(const float2*)(w + 384);
                        a00 = fmaf(hk, w0.x, a00); a10 = fmaf(hk, w0.y, a10);
                        a01 = fmaf(hk, w1.x, a01); a11 = fmaf(hk, w1.y, a11);
                        a02 = fmaf(hk, w2.x, a02); a12 = fmaf(hk, w2.y, a12);
                        a03 = fmaf(hk, w3.x, a03); a13 = fmaf(hk, w3.y, a13);
                    }
                }
                __syncthreads();
                {
                    float c_ = c0s[row][j0];
                    float cn = sigf(a01) * c_ + sigf(a00) * tanhfast(a02);
                    float hn = sigf(a03) * tanhfast(cn);
                    c0s[row][j0] = cn; h0s[row][j0] = hn;
                    float c2 = c0s[row][j0 + 1];
                    float cn2 = sigf(a11) * c2 + sigf(a10) * tanhfast(a12);
                    float hn2 = sigf(a13) * tanhfast(cn2);
                    c0s[row][j0 + 1] = cn2; h0s[row][j0 + 1] = hn2;
                }
                __syncthreads();
                // ---------- layer 1: gates = h0_new @ Wih1^T + h1 @ Whh1^T + bias1 ----------
                {
                    float2 v0 = *(const float2*)(bias1 + j0);
                    float2 v1 = *(const float2*)(bias1 + 128 + j0);
                    float2 v2 = *(const float2*)(bias1 + 256 + j0);
                    float2 v3 = *(const float2*)(bias1 + 384 + j0);
                    a00 = v0.x; a10 = v0.y; a01 = v1.x; a11 = v1.y;
                    a02 = v2.x; a12 = v2.y; a03 = v3.x; a13 = v3.y;
                }
                for (int k = 0; k < 128; k += 4) {
                    float4 hv = *(const float4*)&h0s[row][k];
                    float ha[4] = {hv.x, hv.y, hv.z, hv.w};
                    const float* wb = WihT1 + (size_t)k * 512 + j0;
#pragma unroll
                    for (int kk = 0; kk < 4; ++kk) {
                        float hk = ha[kk];
                        const float* w = wb + kk * 512;
                        float2 w0 = *(const float2*)(w);
                        float2 w1 = *(const float2*)(w + 128);
                        float2 w2 = *(const float2*)(w + 256);
                        float2 w3 = *(const float2*)(w + 384);
                        a00 = fmaf(hk, w0.x, a00); a10 = fmaf(hk, w0.y, a10);
                        a01 = fmaf(hk, w1.x, a01); a11 = fmaf(hk, w1.y, a11);
                        a02 = fmaf(hk, w2.x, a02); a12 = fmaf(hk, w2.y, a12);
                        a03 = fmaf(hk, w3.x, a03); a13 = fmaf(hk, w3.y, a13);
                    }
                }
                for (int k = 0; k < 128; k += 4) {
                    float4 hv = *(const float4*)&h1s[row][k];
                    float ha[4] = {hv.x, hv.y, hv.z, hv.w};
                    const float* wb = WhhT1 + (size_t)k * 512 + j0;
#pragma unroll
                    for (int kk = 0; kk < 4; ++kk) {
                        float hk = ha[kk];
                        const float* w = wb + kk * 512;
                        float2 w0 = *(const float2*)(w);
                        float2 w1 = *(const float2*)(w + 128);
                        float2 w2 = *(const float2*)(w + 256);
                        float2 w3 = *(const float2*)(w + 384);
                        a00 = fmaf(hk, w0.x, a00); a10 = fmaf(hk, w0.y, a10);
                        a01 = fmaf(hk, w1.x, a01); a11 = fmaf(hk, w1.y, a11);
                        a02 = fmaf(hk, w2.x, a02); a12 = fmaf(hk, w2.y, a12);
                        a03 = fmaf(hk, w3.x, a03); a13 = fmaf(hk, w3.y, a13);
                    }
                }
                __syncthreads();
                {
                    float c_ = c1s[row][j0];
                    float cn = sigf(a01) * c_ + sigf(a00) * tanhfast(a02);
                    float hn = sigf(a03) * tanhfast(cn);
                    c1s[row][j0] = cn; h1s[row][j0] = hn;
                    float c2 = c1s[row][j0 + 1];
                    float cn2 = sigf(a11) * c2 + sigf(a10) * tanhfast(a12);
                    float hn2 = sigf(a13) * tanhfast(cn2);
                    c1s[row][j0 + 1] = cn2; h1s[row][j0 + 1] = hn2;
                }
                __syncthreads();
            }
            // M[hist] = h1 (last timestep's top-layer output)
            *(float2*)&Ms[row][hist][j0] = *(const float2*)&h1s[row][j0];
            __syncthreads();
        }

        // ---------------- attention for round r ----------------
        {   // q[row][j0..j0+1] from M[row][r]
            float a0 = bq[j0], a1 = bq[j0 + 1];
            const float* mrow = &Ms[row][r][0];
            for (int k = 0; k < 128; ++k) {
                float m = mrow[k];
                float2 w = *(const float2*)(WqT + (size_t)k * 128 + j0);
                a0 = fmaf(m, w.x, a0); a1 = fmaf(m, w.y, a1);
            }
            qs[row][j0] = a0; qs[row][j0 + 1] = a1;
        }
        for (int kk = 0; kk <= r; ++kk) {
            float a0 = bk[j0], a1 = bk[j0 + 1];
            const float* mrow = &Ms[row][kk][0];
            for (int k = 0; k < 128; ++k) {
                float m = mrow[k];
                float2 w = *(const float2*)(WkT + (size_t)k * 128 + j0);
                a0 = fmaf(m, w.x, a0); a1 = fmaf(m, w.y, a1);
            }
            Kms[row][kk][j0] = a0; Kms[row][kk][j0 + 1] = a1;
        }
        __syncthreads();
        // scores: wave(=row) shuffle reduction over 128 dims
        for (int kk = 0; kk <= r; ++kk) {
            float p = qs[row][j0] * Kms[row][kk][j0] + qs[row][j0 + 1] * Kms[row][kk][j0 + 1];
            p += __shfl_xor(p, 32); p += __shfl_xor(p, 16); p += __shfl_xor(p, 8);
            p += __shfl_xor(p, 4);  p += __shfl_xor(p, 2);  p += __shfl_xor(p, 1);
            if (jp == 0) scs[row][kk] = p * 0.088388347648318447f;  // 1/sqrt(128)
        }
        __syncthreads();
        {   // softmax (redundant per lane) + attention output (with -1 padding)
            float mx = -3.4e38f;
            for (int kk = 0; kk <= r; ++kk) mx = fmaxf(mx, scs[row][kk]);
            float sum = 0.0f;
            for (int kk = 0; kk <= r; ++kk) sum += __expf(scs[row][kk] - mx);
            float inv = 1.0f / sum;
            float myv = 0.0f;
            if (jp <= r) myv = __expf(scs[row][jp] - mx) * inv;
            if (jp <= r) scs[row][jp] = myv;   // loads above precede this store (lockstep wave)
            if (jp < 10) out[OFF_ATT + (size_t)b * 100 + (size_t)r * 10 + jp] = (jp <= r) ? myv : -1.0f;
        }
        __syncthreads();
        // V head + weighted sum into output
        float o0 = 0.0f, o1 = 0.0f;
        for (int kk = 0; kk <= r; ++kk) {
            __syncthreads();
            {
                int rw = tid >> 6, uj = tid & 63;
                float a = bo1[uj];
                const float* mrow = &Ms[rw][kk][0];
                for (int k = 0; k < 128; ++k) a = fmaf(mrow[k], Wo1T[(size_t)k * 64 + uj], a);
                us[rw][uj] = fmaxf(a, 0.0f);
            }
            __syncthreads();
            if (jp == 0) {
                float v0 = bo2[0], v1 = bo2[1];
                for (int k = 0; k < 64; ++k) {
                    float uu = us[row][k];
                    v0 = fmaf(uu, Wo2[k], v0);
                    v1 = fmaf(uu, Wo2[64 + k], v1);
                }
                float mv = fmaxf(v0, v1);
                float lse = mv + __logf(__expf(v0 - mv) + __expf(v1 - mv));
                float s = scs[row][kk];
                o0 = fmaf(s, v0 - lse, o0);
                o1 = fmaf(s, v1 - lse, o1);
            }
        }
        if (jp == 0) {
            out[(size_t)b * 20 + r * 2 + 0] = o0;
            out[(size_t)b * 20 + r * 2 + 1] = o1;
        }
        __syncthreads();
    }

    // final h, c (flat [L,B,H] reinterpretation)
    {
        const size_t base = (size_t)b * 128 + j0;
        *(float2*)(out + OFF_H + base)          = *(const float2*)&h0s[row][j0];
        *(float2*)(out + OFF_H + 131072 + base) = *(const float2*)&h1s[row][j0];
        *(float2*)(out + OFF_C + base)          = *(const float2*)&c0s[row][j0];
        *(float2*)(out + OFF_C + 131072 + base) = *(const float2*)&c1s[row][j0];
    }
}

// ---------------- launch ----------------
extern "C" void kernel_launch(void* const* d_in, const int* in_sizes, int n_in,
                              void* d_out, int out_size, void* d_ws, size_t ws_size,
                              hipStream_t stream) {
    const float* input_vec = (const float*)d_in[0];
    const float* gv    = (const float*)d_in[1];
    const float* uv    = (const float*)d_in[2];
    const float* W_in1 = (const float*)d_in[3];
    const float* b_in1 = (const float*)d_in[4];
    const float* W_in2 = (const float*)d_in[5];
    const float* b_in2 = (const float*)d_in[6];
    const float* Wq    = (const float*)d_in[7];
    const float* bq    = (const float*)d_in[8];
    const float* Wk    = (const float*)d_in[9];
    const float* bk    = (const float*)d_in[10];
    const float* Wih   = (const float*)d_in[11];
    const float* Whh   = (const float*)d_in[12];
    const float* bih   = (const float*)d_in[13];
    const float* bhh   = (const float*)d_in[14];
    const float* Wo1   = (const float*)d_in[15];
    const float* bo1   = (const float*)d_in[16];
    const float* Wo2   = (const float*)d_in[17];
    const float* bo2   = (const float*)d_in[18];
    float* out = (float*)d_out;
    float* ws  = (float*)d_ws;

    // workspace layout (floats). tmp1 and xg0 share region 0 (tmp1 dead before xg0 written).
    float* tmp1    = ws + 0;          // [10240][1024]
    float* xg0     = ws + 0;          // [10240][512]
    float* lstm_in = ws + 10485760;   // [10240][128]
    float* WhhT0   = ws + 11796480;   // [128][512]
    float* WihT1   = ws + 11862016;
    float* WhhT1   = ws + 11927552;
    float* WqT     = ws + 11993088;   // [128][128]
    float* WkT     = ws + 12009472;
    float* Wo1T    = ws + 12025856;   // [128][64]
    float* bias0c  = ws + 12034048;   // [512]
    float* bias1c  = ws + 12034560;   // [512]

    transpose_k<<<256, 256, 0, stream>>>(Whh, WhhT0, 512, 128);
    transpose_k<<<256, 256, 0, stream>>>(Wih + 65536, WihT1, 512, 128);
    transpose_k<<<256, 256, 0, stream>>>(Whh + 65536, WhhT1, 512, 128);
    transpose_k<<<64, 256, 0, stream>>>(Wq, WqT, 128, 128);
    transpose_k<<<64, 256, 0, stream>>>(Wk, WkT, 128, 128);
    transpose_k<<<32, 256, 0, stream>>>(Wo1, Wo1T, 64, 128);
    bias_comb_k<<<2, 256, 0, stream>>>(bih, bhh, bias0c, bias1c);

    // input MLP + layer-0 input-gate precompute
    gemm_bias_act_k<<<dim3(16, 160), 256, 0, stream>>>(input_vec, W_in1, b_in1, tmp1, 10240, 1024, 512, 1);
    gemm_bias_act_k<<<dim3(2, 160), 256, 0, stream>>>(tmp1, W_in2, b_in2, lstm_in, 10240, 128, 1024, 1);
    gemm_bias_act_k<<<dim3(8, 160), 256, 0, stream>>>(lstm_in, Wih, bias0c, xg0, 10240, 512, 128, 0);

    recurrent_k<<<256, 256, 0, stream>>>(xg0, WhhT0, WihT1, WhhT1, bias1c,
                                         WqT, bq, WkT, bk, Wo1T, bo1, Wo2, bo2,
                                         gv, uv, out);
}

// Round 2
// 3433.833 us; speedup vs baseline: 3.0291x; 3.0291x over previous
//
#include <hip/hip_runtime.h>
#include <stdint.h>

// ---------------- constants ----------------
static const size_t OFF_ATT = 20480;    // out: 1024*10*2
static const size_t OFF_H   = 122880;   // + att 1024*10*10
static const size_t OFF_C   = 385024;   // + h 2*1024*128

typedef _Float16 half2_t __attribute__((ext_vector_type(2)));

__device__ __forceinline__ float sigf(float x) { return 1.0f / (1.0f + __expf(-x)); }
// tanh(x) = 1 - 2/(e^{2x}+1); safe at +/-inf, ~1e-7 abs err.
__device__ __forceinline__ float tanhfast(float x) { return 1.0f - 2.0f / (__expf(2.0f * x) + 1.0f); }

__device__ __forceinline__ float fdot2(uint32_t w, uint32_t h, float acc) {
    return __builtin_amdgcn_fdot2(__builtin_bit_cast(half2_t, w), __builtin_bit_cast(half2_t, h), acc, false);
}

// ---------------- prep kernels ----------------
// W[R][C] -> Tm[C][R]
__global__ __launch_bounds__(256) void transpose_k(const float* __restrict__ W, float* __restrict__ Tm, int R, int C) {
    int idx = blockIdx.x * 256 + threadIdx.x;
    if (idx < R * C) {
        int r = idx / C, c = idx - r * C;
        Tm[(size_t)c * R + r] = W[idx];
    }
}

__global__ void bias_comb_k(const float* __restrict__ bih, const float* __restrict__ bhh,
                            float* __restrict__ b0, float* __restrict__ b1) {
    int i = blockIdx.x * 256 + threadIdx.x;
    if (i < 512) {
        b0[i] = bih[i] + bhh[i];
        b1[i] = bih[512 + i] + bhh[512 + i];
    }
}

// pack fp32 W[512][128] -> P[64][512] dwords; P[kp][j] = half2(W[j][2kp], W[j][2kp+1])
__global__ __launch_bounds__(256) void pack_w_k(const float* __restrict__ W, uint32_t* __restrict__ P) {
    int idx = blockIdx.x * 256 + threadIdx.x;   // 32768 total
    int kp = idx >> 9, j = idx & 511;
    half2_t h;
    h.x = (_Float16)W[j * 128 + 2 * kp];
    h.y = (_Float16)W[j * 128 + 2 * kp + 1];
    P[idx] = __builtin_bit_cast(uint32_t, h);
}

// ---------------- tiled GEMM: C = act(A[M,K] @ B[N,K]^T + bias[N]) ----------------
__global__ __launch_bounds__(256) void gemm_bias_act_k(const float* __restrict__ A, const float* __restrict__ Bm,
                                                       const float* __restrict__ bias, float* __restrict__ C,
                                                       int M, int N, int K, int relu) {
    __shared__ float As[16][68];
    __shared__ float Bs[16][68];
    int tid = threadIdx.x;
    int tx = tid & 15, ty = tid >> 4;
    int bm = blockIdx.y << 6, bn = blockIdx.x << 6;
    int lr = tid >> 2, lk = (tid & 3) << 2;
    float acc[4][4] = {};
    for (int k0 = 0; k0 < K; k0 += 16) {
        __syncthreads();
        float4 av = *(const float4*)(A + (size_t)(bm + lr) * K + k0 + lk);
        float4 bv = *(const float4*)(Bm + (size_t)(bn + lr) * K + k0 + lk);
        As[lk + 0][lr] = av.x; As[lk + 1][lr] = av.y; As[lk + 2][lr] = av.z; As[lk + 3][lr] = av.w;
        Bs[lk + 0][lr] = bv.x; Bs[lk + 1][lr] = bv.y; Bs[lk + 2][lr] = bv.z; Bs[lk + 3][lr] = bv.w;
        __syncthreads();
#pragma unroll
        for (int kk = 0; kk < 16; ++kk) {
            float a[4], b[4];
#pragma unroll
            for (int i = 0; i < 4; ++i) a[i] = As[kk][ty * 4 + i];
#pragma unroll
            for (int j = 0; j < 4; ++j) b[j] = Bs[kk][tx * 4 + j];
#pragma unroll
            for (int i = 0; i < 4; ++i)
#pragma unroll
                for (int j = 0; j < 4; ++j) acc[i][j] = fmaf(a[i], b[j], acc[i][j]);
        }
    }
#pragma unroll
    for (int i = 0; i < 4; ++i)
#pragma unroll
        for (int j = 0; j < 4; ++j) {
            float v = acc[i][j] + bias[bn + tx * 4 + j];
            if (relu) v = fmaxf(v, 0.0f);
            C[(size_t)(bm + ty * 4 + i) * N + bn + tx * 4 + j] = v;
        }
}

// ---------------- main sequential kernel ----------------
// 256 blocks x 512 threads (8 waves, 2/SIMD). Block owns 4 batch rows.
// Weight columns live in REGISTERS as packed fp16 pairs (192 VGPRs);
// inner product via v_dot2_f32_f16 with h broadcast from LDS.
__global__ __launch_bounds__(512, 2) void recurrent2_k(
    const float* __restrict__ xg0,      // [1024*10][512] = lstm_in@Wih0^T + bih0 + bhh0 (f32)
    const uint32_t* __restrict__ Wp0,   // packed Whh0 [64][512]
    const uint32_t* __restrict__ Wp1,   // packed Wih1
    const uint32_t* __restrict__ Wp2,   // packed Whh1
    const float* __restrict__ bias1,    // [512] bih1+bhh1
    const float* __restrict__ WqT, const float* __restrict__ bq,
    const float* __restrict__ WkT, const float* __restrict__ bk,
    const float* __restrict__ Wo1T, const float* __restrict__ bo1,
    const float* __restrict__ Wo2, const float* __restrict__ bo2,
    const float* __restrict__ gv, const float* __restrict__ uv,
    float* __restrict__ out) {
    __shared__ uint32_t hs0[64][4];     // packed h0 pairs: [kp][row], half idx = kp*8+row*2+(hj&1)
    __shared__ uint32_t hs1[64][4];
    __shared__ float gates[4][512];
    __shared__ float Ms[4][10][128];
    __shared__ float qs[4][128];
    __shared__ float Kms[4][10][128];
    __shared__ float us[4][64];
    __shared__ float scs[4][10];

    const int tid = threadIdx.x;        // matmul role: gate column j = tid
    const int row = tid >> 7;           // cell role: (row, hj)
    const int hj  = tid & 127;
    const int b0  = blockIdx.x << 2;
    const int b   = b0 + row;

    // weights -> registers (persist across all 229 steps)
    uint32_t w0[64], w1[64], w2[64];
#pragma unroll
    for (int kp = 0; kp < 64; ++kp) {
        w0[kp] = Wp0[kp * 512 + tid];
        w1[kp] = Wp1[kp * 512 + tid];
        w2[kp] = Wp2[kp * 512 + tid];
    }
    const float bs1 = bias1[tid];

    // state init (gv/uv flat [2][1024][128] reinterpretation)
    float h0r = gv[(size_t)b * 128 + hj];
    float h1r = gv[131072 + (size_t)b * 128 + hj];
    float c0r = uv[(size_t)b * 128 + hj];
    float c1r = uv[131072 + (size_t)b * 128 + hj];
    {
        _Float16* p0 = (_Float16*)hs0;
        _Float16* p1 = (_Float16*)hs1;
        int o = (hj >> 1) * 8 + row * 2 + (hj & 1);
        p0[o] = (_Float16)h0r;
        p1[o] = (_Float16)h1r;
    }
    __syncthreads();

    auto lstm_step = [&](int t) {
        // ---- layer 0: gates = dot2(Whh0_col, h0) + xg0 ----
        const float* xgp = xg0 + ((size_t)b0 * 10 + t) * 512 + tid;
        float x0 = xgp[0], x1 = xgp[5120], x2 = xgp[10240], x3 = xgp[15360];
        float a0 = 0.f, a1 = 0.f, a2 = 0.f, a3 = 0.f;
#pragma unroll
        for (int kp = 0; kp < 64; ++kp) {
            uint4 hv = *(const uint4*)&hs0[kp][0];
            a0 = fdot2(w0[kp], hv.x, a0);
            a1 = fdot2(w0[kp], hv.y, a1);
            a2 = fdot2(w0[kp], hv.z, a2);
            a3 = fdot2(w0[kp], hv.w, a3);
        }
        gates[0][tid] = a0 + x0; gates[1][tid] = a1 + x1;
        gates[2][tid] = a2 + x2; gates[3][tid] = a3 + x3;
        __syncthreads();
        {   // cell 0
            float gi = gates[row][hj], gf = gates[row][128 + hj];
            float gg = gates[row][256 + hj], go = gates[row][384 + hj];
            float cn = sigf(gf) * c0r + sigf(gi) * tanhfast(gg);
            float hn = sigf(go) * tanhfast(cn);
            c0r = cn; h0r = hn;
            ((_Float16*)hs0)[(hj >> 1) * 8 + row * 2 + (hj & 1)] = (_Float16)hn;
        }
        __syncthreads();
        // ---- layer 1: gates = dot2(Wih1_col, h0new) + dot2(Whh1_col, h1) + bias1 ----
        a0 = bs1; a1 = bs1; a2 = bs1; a3 = bs1;
#pragma unroll
        for (int kp = 0; kp < 64; ++kp) {
            uint4 hv = *(const uint4*)&hs0[kp][0];
            a0 = fdot2(w1[kp], hv.x, a0);
            a1 = fdot2(w1[kp], hv.y, a1);
            a2 = fdot2(w1[kp], hv.z, a2);
            a3 = fdot2(w1[kp], hv.w, a3);
        }
#pragma unroll
        for (int kp = 0; kp < 64; ++kp) {
            uint4 hv = *(const uint4*)&hs1[kp][0];
            a0 = fdot2(w2[kp], hv.x, a0);
            a1 = fdot2(w2[kp], hv.y, a1);
            a2 = fdot2(w2[kp], hv.z, a2);
            a3 = fdot2(w2[kp], hv.w, a3);
        }
        gates[0][tid] = a0; gates[1][tid] = a1; gates[2][tid] = a2; gates[3][tid] = a3;
        __syncthreads();
        {   // cell 1
            float gi = gates[row][hj], gf = gates[row][128 + hj];
            float gg = gates[row][256 + hj], go = gates[row][384 + hj];
            float cn = sigf(gf) * c1r + sigf(gi) * tanhfast(gg);
            float hn = sigf(go) * tanhfast(cn);
            c1r = cn; h1r = hn;
            ((_Float16*)hs1)[(hj >> 1) * 8 + row * 2 + (hj & 1)] = (_Float16)hn;
        }
        __syncthreads();
    };

    for (int r = 0; r < 10; ++r) {
        for (int hist = 0; hist <= r; ++hist) {
            const int t0 = (hist <= 1) ? 0 : hist;  // quirk: hist==1 reruns full prefix
            for (int t = t0; t <= r; ++t) lstm_step(t);
            Ms[row][hist][hj] = h1r;
        }
        __syncthreads();

        // ---------------- attention for round r ----------------
        {   // q[row][hj], K rows
            float aq = bq[hj];
            const float* mrow = &Ms[row][r][0];
            for (int k = 0; k < 128; ++k) aq = fmaf(mrow[k], WqT[k * 128 + hj], aq);
            qs[row][hj] = aq;
            for (int kk = 0; kk <= r; ++kk) {
                float ak = bk[hj];
                const float* m2 = &Ms[row][kk][0];
                for (int k = 0; k < 128; ++k) ak = fmaf(m2[k], WkT[k * 128 + hj], ak);
                Kms[row][kk][hj] = ak;
            }
        }
        __syncthreads();
        // raw scores: one thread per (row, kk)
        if (tid < 4 * (r + 1)) {
            int rw = tid / (r + 1), kk = tid - rw * (r + 1);
            float p = 0.f;
            const float* qp = &qs[rw][0];
            const float* kp_ = &Kms[rw][kk][0];
            for (int k = 0; k < 128; ++k) p = fmaf(qp[k], kp_[k], p);
            scs[rw][kk] = p * 0.088388347648318447f;   // 1/sqrt(128)
        }
        __syncthreads();
        // softmax + attention output (threads 0..39, all in wave 0 => lockstep)
        if (tid < 40) {
            int rw = tid / 10, jp = tid - rw * 10;
            float mx = -3.4e38f;
            for (int kk = 0; kk <= r; ++kk) mx = fmaxf(mx, scs[rw][kk]);
            float sum = 0.f;
            for (int kk = 0; kk <= r; ++kk) sum += __expf(scs[rw][kk] - mx);
            float inv = 1.0f / sum;
            float myv = (jp <= r) ? __expf(scs[rw][jp] - mx) * inv : 0.0f;
            if (jp <= r) scs[rw][jp] = myv;  // reads above precede store (single-wave lockstep)
            out[OFF_ATT + (size_t)(b0 + rw) * 100 + (size_t)r * 10 + jp] = (jp <= r) ? myv : -1.0f;
        }
        __syncthreads();
        // V head + weighted sum
        float o0 = 0.f, o1 = 0.f;
        for (int kk = 0; kk <= r; ++kk) {
            if (tid < 256) {
                int rw = tid >> 6, uj = tid & 63;
                float a = bo1[uj];
                const float* mrow = &Ms[rw][kk][0];
                for (int k = 0; k < 128; ++k) a = fmaf(mrow[k], Wo1T[k * 64 + uj], a);
                us[rw][uj] = fmaxf(a, 0.f);
            }
            __syncthreads();
            if (tid < 4) {
                float v0 = bo2[0], v1 = bo2[1];
                for (int k = 0; k < 64; ++k) {
                    float uu = us[tid][k];
                    v0 = fmaf(uu, Wo2[k], v0);
                    v1 = fmaf(uu, Wo2[64 + k], v1);
                }
                float mv = fmaxf(v0, v1);
                float lse = mv + __logf(__expf(v0 - mv) + __expf(v1 - mv));
                float s = scs[tid][kk];
                o0 = fmaf(s, v0 - lse, o0);
                o1 = fmaf(s, v1 - lse, o1);
            }
            __syncthreads();
        }
        if (tid < 4) {
            out[(size_t)(b0 + tid) * 20 + r * 2 + 0] = o0;
            out[(size_t)(b0 + tid) * 20 + r * 2 + 1] = o1;
        }
    }

    // final h, c
    out[OFF_H + (size_t)b * 128 + hj]          = h0r;
    out[OFF_H + 131072 + (size_t)b * 128 + hj] = h1r;
    out[OFF_C + (size_t)b * 128 + hj]          = c0r;
    out[OFF_C + 131072 + (size_t)b * 128 + hj] = c1r;
}

// ---------------- launch ----------------
extern "C" void kernel_launch(void* const* d_in, const int* in_sizes, int n_in,
                              void* d_out, int out_size, void* d_ws, size_t ws_size,
                              hipStream_t stream) {
    const float* input_vec = (const float*)d_in[0];
    const float* gv    = (const float*)d_in[1];
    const float* uv    = (const float*)d_in[2];
    const float* W_in1 = (const float*)d_in[3];
    const float* b_in1 = (const float*)d_in[4];
    const float* W_in2 = (const float*)d_in[5];
    const float* b_in2 = (const float*)d_in[6];
    const float* Wq    = (const float*)d_in[7];
    const float* bq    = (const float*)d_in[8];
    const float* Wk    = (const float*)d_in[9];
    const float* bk    = (const float*)d_in[10];
    const float* Wih   = (const float*)d_in[11];
    const float* Whh   = (const float*)d_in[12];
    const float* bih   = (const float*)d_in[13];
    const float* bhh   = (const float*)d_in[14];
    const float* Wo1   = (const float*)d_in[15];
    const float* bo1   = (const float*)d_in[16];
    const float* Wo2   = (const float*)d_in[17];
    const float* bo2   = (const float*)d_in[18];
    float* out = (float*)d_out;
    float* ws  = (float*)d_ws;

    // workspace layout (float units). tmp1 and xg0 share region 0.
    float* tmp1    = ws + 0;          // [10240][1024]
    float* xg0     = ws + 0;          // [10240][512]
    float* lstm_in = ws + 10485760;   // [10240][128]
    uint32_t* Wp0  = (uint32_t*)(ws + 11796480);   // [64][512]
    uint32_t* Wp1  = (uint32_t*)(ws + 11829248);
    uint32_t* Wp2  = (uint32_t*)(ws + 11862016);
    float* WqT     = ws + 11894784;   // [128][128]
    float* WkT     = ws + 11911168;
    float* Wo1T    = ws + 11927552;   // [128][64]
    float* bias0c  = ws + 11935744;   // [512]
    float* bias1c  = ws + 11936256;   // [512]

    pack_w_k<<<128, 256, 0, stream>>>(Whh, Wp0);            // layer-0 Whh
    pack_w_k<<<128, 256, 0, stream>>>(Wih + 65536, Wp1);    // layer-1 Wih
    pack_w_k<<<128, 256, 0, stream>>>(Whh + 65536, Wp2);    // layer-1 Whh
    transpose_k<<<64, 256, 0, stream>>>(Wq, WqT, 128, 128);
    transpose_k<<<64, 256, 0, stream>>>(Wk, WkT, 128, 128);
    transpose_k<<<32, 256, 0, stream>>>(Wo1, Wo1T, 64, 128);
    bias_comb_k<<<2, 256, 0, stream>>>(bih, bhh, bias0c, bias1c);

    // input MLP + layer-0 input-gate precompute (fp32)
    gemm_bias_act_k<<<dim3(16, 160), 256, 0, stream>>>(input_vec, W_in1, b_in1, tmp1, 10240, 1024, 512, 1);
    gemm_bias_act_k<<<dim3(2, 160), 256, 0, stream>>>(tmp1, W_in2, b_in2, lstm_in, 10240, 128, 1024, 1);
    gemm_bias_act_k<<<dim3(8, 160), 256, 0, stream>>>(lstm_in, Wih, bias0c, xg0, 10240, 512, 128, 0);

    recurrent2_k<<<256, 512, 0, stream>>>(xg0, Wp0, Wp1, Wp2, bias1c,
                                          WqT, bq, WkT, bk, Wo1T, bo1, Wo2, bo2,
                                          gv, uv, out);
}